// Round 16
// baseline (96.349 us; speedup 1.0000x reference)
//
#include <hip/hip_runtime.h>

#define N_NODES 10000
#define N_EDGES 640000
#define D 128
#define MAXDEG 128
#define NBUCK 157            // ceil(10000 / 64) buckets of 64 dst nodes
#define BCAP 6144            // bucket capacity; mean 4076 -> huge margin
#define EPB2 1024            // edges per bin block: 625 blocks * 1024 = 640000
#define ZROW 10000           // zero-row index used for adj padding

typedef unsigned int uint;
typedef unsigned short u16;
typedef short bf16x8 __attribute__((ext_vector_type(8)));
typedef float f32x4 __attribute__((ext_vector_type(4)));

__device__ __forceinline__ u16 f2bf(float f) {
    uint u = __float_as_uint(f);
    return (u16)((u + 0x7fffu + ((u >> 16) & 1u)) >> 16);   // round-nearest-even
}
__device__ __forceinline__ float bflo(uint v) { return __uint_as_float(v << 16); }
__device__ __forceinline__ float bfhi(uint v) { return __uint_as_float(v & 0xffff0000u); }

// ---------------------------------------------------------------------------
// Pass 1 v2: bin 1024 edges/block into NBUCK dense global buckets.
// uint4-vectorized edge loads; LDS-staged bucket-sorted output so each
// bucket's global segment is written as one contiguous run (fixes the ~6%
// write-line utilization of per-thread scattered 4B stores).
__global__ __launch_bounds__(256)
void binp1_kernel(const void* __restrict__ ei, int* __restrict__ gcount,
                  uint* __restrict__ gbucket) {
    __shared__ int hist[NBUCK];
    __shared__ int scan_[NBUCK];
    __shared__ int gbase[NBUCK];
    __shared__ uint stage[EPB2];
    __shared__ int s_is32;
    const int t = threadIdx.x;
    if (t < NBUCK) hist[t] = 0;
    if (t == 0) s_is32 = 0;
    __syncthreads();
    const int e0 = blockIdx.x * EPB2;
    // dtype probe: int64 -> odd 32b words (id high halves) are all 0
    if (((const int*)ei)[2 * (e0 + t) + 1] != 0) s_is32 = 1;   // benign race
    __syncthreads();
    const int is32 = s_is32;

    uint srcs[4], dsts[4];
    if (is32) {
        uint4 s4 = ((const uint4*)ei)[(e0 >> 2) + t];
        uint4 d4 = ((const uint4*)ei)[((N_EDGES + e0) >> 2) + t];
        srcs[0] = s4.x; srcs[1] = s4.y; srcs[2] = s4.z; srcs[3] = s4.w;
        dsts[0] = d4.x; dsts[1] = d4.y; dsts[2] = d4.z; dsts[3] = d4.w;
    } else {
        const uint4* p = (const uint4*)ei;               // 16B = 2 int64 ids
        uint4 a  = p[(e0 >> 1) + 2 * t];
        uint4 b2 = p[(e0 >> 1) + 2 * t + 1];
        uint4 c4 = p[((N_EDGES + e0) >> 1) + 2 * t];
        uint4 d4 = p[((N_EDGES + e0) >> 1) + 2 * t + 1];
        srcs[0] = a.x;  srcs[1] = a.z;  srcs[2] = b2.x; srcs[3] = b2.z;
        dsts[0] = c4.x; dsts[1] = c4.z; dsts[2] = d4.x; dsts[3] = d4.z;
    }
    uint pk[4]; int rk[4];
#pragma unroll
    for (int i = 0; i < 4; ++i) {
        pk[i] = (dsts[i] << 16) | srcs[i];
        rk[i] = atomicAdd(&hist[dsts[i] >> 6], 1);
    }
    __syncthreads();
    if (t == 0) {                                        // block-local excl scan
        int c = 0;
        for (int u = 0; u < NBUCK; ++u) { scan_[u] = c; c += hist[u]; }
    }
    __syncthreads();
    if (t < NBUCK) gbase[t] = atomicAdd(&gcount[t], hist[t]);
#pragma unroll
    for (int i = 0; i < 4; ++i)
        stage[scan_[(int)(dsts[i] >> 6)] + rk[i]] = pk[i];
    __syncthreads();
    for (int i = t; i < EPB2; i += 256) {                // contiguous runs out
        uint v = stage[i];
        int bkt = (int)(v >> 22);
        int pos = gbase[bkt] + (i - scan_[bkt]);
        if (pos < BCAP) gbucket[(size_t)bkt * BCAP + pos] = v;
    }
}

// ---------------------------------------------------------------------------
// Fused prep (proven R9): [0,157) counting-sort buckets -> padded adj (pad =
// ZROW) + deg; [157,782) cast x -> packed bf16; [782,1038) build WT;
// 1038 zeroes the padding zero-rows of xb2 AND yb2.
__global__ __launch_bounds__(256)
void prep_kernel(const int* __restrict__ gcount, const uint* __restrict__ gbucket,
                 u16* __restrict__ adj, int* __restrict__ deg_g,
                 const float* __restrict__ x, uint* __restrict__ xb2,
                 uint* __restrict__ yb2,
                 const float* __restrict__ Wl0, const float* __restrict__ Wr0,
                 const float* __restrict__ Wl1, const float* __restrict__ Wr1,
                 u16* __restrict__ WT0, u16* __restrict__ WT1) {
    const int b = blockIdx.x;
    const int t = threadIdx.x;
    __shared__ __align__(16) u16 tile[64][MAXDEG];   // 16 KB
    __shared__ int cur[64];
    if (b < NBUCK) {
        uint* tw = (uint*)&tile[0][0];               // pad pattern = ZROW|ZROW
#pragma unroll
        for (int q = 0; q < 16; ++q) tw[t + q * 256] = ((uint)ZROW << 16) | ZROW;
        if (t < 64) cur[t] = 0;
        __syncthreads();
        const int total = min(gcount[b], BCAP);
        for (int e = t; e < total; e += 256) {
            uint pk = gbucket[(size_t)b * BCAP + e];
            int ln = (int)((pk >> 16) & 63u);
            int r = atomicAdd(&cur[ln], 1);
            if (r < MAXDEG) tile[ln][r] = (u16)(pk & 0xffffu);
        }
        __syncthreads();
        const int node0 = b * 64;
        if (t < 64 && node0 + t < N_NODES) deg_g[node0 + t] = cur[t];
        const uint4* ts = (const uint4*)&tile[0][0];
#pragma unroll
        for (int q = 0; q < 4; ++q) {
            int i = t + q * 256;
            int node = node0 + (i >> 4);
            if (node < N_NODES) ((uint4*)(adj + (size_t)node * MAXDEG))[i & 15] = ts[i];
        }
    } else if (b < NBUCK + 625) {
        int idx = (b - NBUCK) * 256 + t;             // 0..159999, exact
        const float4* p = (const float4*)x + (size_t)idx * 2;
        float4 a = p[0], bb = p[1];
        uint4 r;
        r.x = (uint)f2bf(a.x) | ((uint)f2bf(a.y) << 16);
        r.y = (uint)f2bf(a.z) | ((uint)f2bf(a.w) << 16);
        r.z = (uint)f2bf(bb.x) | ((uint)f2bf(bb.y) << 16);
        r.w = (uint)f2bf(bb.z) | ((uint)f2bf(bb.w) << 16);
        ((uint4*)xb2)[idx] = r;
    } else if (b < NBUCK + 625 + 256) {
        int b2 = b - (NBUCK + 625);
        int layer = b2 >> 7, d = b2 & 127, k = t;
        const float* Wl = layer ? Wl1 : Wl0;
        const float* Wr = layer ? Wr1 : Wr0;
        u16* WT = layer ? WT1 : WT0;
        float v = (k < 128) ? Wl[k * D + d] : Wr[(k - 128) * D + d];
        WT[(size_t)d * 256 + k] = f2bf(v);
    } else {
        if (t < 16) {
            ((uint4*)(xb2 + (size_t)ZROW * 64))[t] = make_uint4(0, 0, 0, 0);
            ((uint4*)(yb2 + (size_t)ZROW * 64))[t] = make_uint4(0, 0, 0, 0);
        }
    }
}

// ---------------------------------------------------------------------------
// Fused gather+gemm layer: 625 blocks x 1024 threads (16 waves).
// Gather: wave w -> node nb+w; v2 loop with next-chunk adj prefetch;
// padding ids hit the zero row; shfl_xor reduce; g==0 lanes write the bf16
// mean row into LDS A (XOR-swizzle (w&7)<<4), g==1 lanes the node's x row.
// Gemm (waves 0..7): wave w -> cols [w*16, w*16+16); A/B share k-map
// k = kk*32 + q*8 + j; C/D col=lane&15, row=(lane>>4)*4+reg [HW-verified].
__global__ __launch_bounds__(1024, 8)
void fused_kernel(const uint* __restrict__ src2, const u16* __restrict__ adj,
                  const int* __restrict__ deg_g, const u16* __restrict__ WT,
                  const float* __restrict__ bias,
                  float* __restrict__ outf /* may be null */,
                  u16* __restrict__ outb /* may be null */) {
    __shared__ __align__(16) u16 A_lds[16 * 256];    // 8 KB
    const int t = threadIdx.x;
    const int w = t >> 6, l = t & 63;
    const int nb = blockIdx.x * 16;
    const int node = nb + w;

    // ---- gather phase (all 16 waves) ----
    {
        const int g = l >> 4, c = l & 15;
        const int half = g >> 1, sh = (g & 1) << 4;
        const int dg = deg_g[node];
        const int cnt = min(dg, MAXDEG);
        const uint4* __restrict__ rowq = (const uint4*)(adj + (size_t)node * MAXDEG);
        uint4 vx;
        if (g == 1) vx = ((const uint4*)(src2 + (size_t)node * 64))[c];  // early
        float acc[8];
#pragma unroll
        for (int i = 0; i < 8; ++i) acc[i] = 0.f;
        const int nch = (cnt + 15) >> 4;
        uint4 wa = rowq[0], wb = rowq[1];            // adj prefetch (row padded)
#pragma unroll 2
        for (int ch = 0; ch < nch; ++ch) {
            uint4 cwa = wa, cwb = wb;
            if (ch + 1 < nch) {                      // prefetch next chunk's adj
                wa = rowq[2 * ch + 2];
                wb = rowq[2 * ch + 3];
            }
            uint a0 = half ? cwa.y : cwa.x;
            uint a1 = half ? cwa.w : cwa.z;
            uint b0 = half ? cwb.y : cwb.x;
            uint b1 = half ? cwb.w : cwb.z;
            uint id0 = (a0 >> sh) & 0xffffu;
            uint id1 = (a1 >> sh) & 0xffffu;
            uint id2 = (b0 >> sh) & 0xffffu;
            uint id3 = (b1 >> sh) & 0xffffu;
            uint4 v0 = ((const uint4*)(src2 + (size_t)id0 * 64))[c];
            uint4 v1 = ((const uint4*)(src2 + (size_t)id1 * 64))[c];
            uint4 v2 = ((const uint4*)(src2 + (size_t)id2 * 64))[c];
            uint4 v3 = ((const uint4*)(src2 + (size_t)id3 * 64))[c];
            acc[0] += bflo(v0.x) + bflo(v1.x) + bflo(v2.x) + bflo(v3.x);
            acc[1] += bfhi(v0.x) + bfhi(v1.x) + bfhi(v2.x) + bfhi(v3.x);
            acc[2] += bflo(v0.y) + bflo(v1.y) + bflo(v2.y) + bflo(v3.y);
            acc[3] += bfhi(v0.y) + bfhi(v1.y) + bfhi(v2.y) + bfhi(v3.y);
            acc[4] += bflo(v0.z) + bflo(v1.z) + bflo(v2.z) + bflo(v3.z);
            acc[5] += bfhi(v0.z) + bfhi(v1.z) + bfhi(v2.z) + bfhi(v3.z);
            acc[6] += bflo(v0.w) + bflo(v1.w) + bflo(v2.w) + bflo(v3.w);
            acc[7] += bfhi(v0.w) + bfhi(v1.w) + bfhi(v2.w) + bfhi(v3.w);
        }
#pragma unroll
        for (int i = 0; i < 8; ++i) {
            float r = acc[i];
            r += __shfl_xor(r, 16, 64);
            r += __shfl_xor(r, 32, 64);
            acc[i] = r;
        }
        char* arow = (char*)A_lds + w * 512;
        const int swz = (w & 7) << 4;
        if (g == 0) {                                // agg -> k 0..127
            float inv = 1.0f / fmaxf((float)dg, 1.0f);
            uint4 o;
            o.x = (uint)f2bf(acc[0] * inv) | ((uint)f2bf(acc[1] * inv) << 16);
            o.y = (uint)f2bf(acc[2] * inv) | ((uint)f2bf(acc[3] * inv) << 16);
            o.z = (uint)f2bf(acc[4] * inv) | ((uint)f2bf(acc[5] * inv) << 16);
            o.w = (uint)f2bf(acc[6] * inv) | ((uint)f2bf(acc[7] * inv) << 16);
            *(uint4*)(arow + ((c * 16) ^ swz)) = o;
        } else if (g == 1) {                         // own x/h row -> k 128..255
            *(uint4*)(arow + ((256 + c * 16) ^ swz)) = vx;
        }
    }
    __syncthreads();

    // ---- gemm phase (waves 0..7; wave w -> cols [w*16, w*16+16)) ----
    if (w < 8) {
        const int lr = l & 15, q = l >> 4;
        f32x4 acc0 = {0.f, 0.f, 0.f, 0.f};
        const u16* wt = WT + (size_t)(w * 16 + lr) * 256;
        const char* abase = (const char*)A_lds + lr * 512;
        const int aswz = (lr & 7) << 4;
#pragma unroll
        for (int kk = 0; kk < 8; ++kk) {
            bf16x8 af = *(const bf16x8*)(abase + ((kk * 64 + q * 16) ^ aswz));
            bf16x8 bf = *(const bf16x8*)(wt + kk * 32 + q * 8);
            acc0 = __builtin_amdgcn_mfma_f32_16x16x32_bf16(af, bf, acc0, 0, 0, 0);
        }
        const int col = w * 16 + lr;
        const float bv = bias[col];
#pragma unroll
        for (int j = 0; j < 4; ++j) {
            const int nd = nb + q * 4 + j;
            float v = acc0[j] + bv;
            v = v > 0.f ? v : expm1f(v);             // ELU alpha=1
            if (outf) outf[(size_t)nd * D + col] = v;
            if (outb) outb[(size_t)nd * D + col] = f2bf(v);
        }
    }
}

// ---------------------------------------------------------------------------
extern "C" void kernel_launch(void* const* d_in, const int* in_sizes, int n_in,
                              void* d_out, int out_size, void* d_ws, size_t ws_size,
                              hipStream_t stream) {
    const float* x   = (const float*)d_in[0];
    const void*  ei  = d_in[1];
    const float* Wl0 = (const float*)d_in[2];
    const float* b0  = (const float*)d_in[3];
    const float* Wr0 = (const float*)d_in[4];
    const float* Wl1 = (const float*)d_in[5];
    const float* b1  = (const float*)d_in[6];
    const float* Wr1 = (const float*)d_in[7];
    float* out = (float*)d_out;

    char* ws = (char*)d_ws;                      // ws ~268 MB, no overlays
    int*  gcount  = (int*)(ws + 1024);           // 628 B
    int*  deg     = (int*)(ws + 4096);           // 40 KB
    u16*  adj     = (u16*)(ws + 65536);          // 2.56 MB
    uint* gbucket = (uint*)(ws + 3145728);       // 3.86 MB
    uint* xb2     = (uint*)(ws + 7340032);       // 2.56 MB + zrow
    uint* yb2     = (uint*)(ws + 10485760);      // 2.56 MB + zrow
    u16*  WT0     = (u16*)(ws + 13631488);       // 64 KB
    u16*  WT1     = (u16*)(ws + 13697024);       // 64 KB

    (void)hipMemsetAsync(ws, 0, 4096, stream);   // gcount

    binp1_kernel<<<625, 256, 0, stream>>>(ei, gcount, gbucket);
    prep_kernel<<<NBUCK + 625 + 256 + 1, 256, 0, stream>>>(
        gcount, gbucket, adj, deg, x, xb2, yb2, Wl0, Wr0, Wl1, Wr1, WT0, WT1);

    // layer 0: gather xb2 -> gemm -> bf16 activations yb2
    fused_kernel<<<625, 1024, 0, stream>>>(xb2, adj, deg, WT0, b0,
                                           (float*)0, (u16*)yb2);
    // layer 1: gather yb2 -> gemm -> f32 final output
    fused_kernel<<<625, 1024, 0, stream>>>(yb2, adj, deg, WT1, b1,
                                           out, (u16*)0);
}

// Round 17
// 77.044 us; speedup vs baseline: 1.2506x; 1.2506x over previous
//
#include <hip/hip_runtime.h>

#define N_NODES 10000
#define N_EDGES 640000
#define D 128
#define MAXDEG 128
#define NBUCK 157            // ceil(10000 / 64) buckets of 64 dst nodes
#define BCAP 6144            // bucket capacity; mean 4076 -> huge margin
#define EPT 5                // edges/thread in pass1: 500 blocks * 256 * 5 = 640000
#define ZROW 10000           // zero-row index used for adj padding

typedef unsigned int uint;
typedef unsigned short u16;
typedef short bf16x8 __attribute__((ext_vector_type(8)));
typedef float f32x4 __attribute__((ext_vector_type(4)));

__device__ __forceinline__ u16 f2bf(float f) {
    uint u = __float_as_uint(f);
    return (u16)((u + 0x7fffu + ((u >> 16) & 1u)) >> 16);   // round-nearest-even
}
__device__ __forceinline__ float bflo(uint v) { return __uint_as_float(v << 16); }
__device__ __forceinline__ float bfhi(uint v) { return __uint_as_float(v & 0xffff0000u); }

__device__ __forceinline__ int edge_at(const void* ei, int is32, int idx) {
    if (is32) return ((const int*)ei)[idx];
    return (int)((const long long*)ei)[idx];
}

// ---------------------------------------------------------------------------
// Pass 1 (proven R9/R15): bin packed (dst<<16|src) edges into NBUCK dense
// global buckets via LDS-hist ranks + one global atomicAdd per (block,bucket).
__global__ __launch_bounds__(256)
void binp1_kernel(const void* __restrict__ ei, int* __restrict__ gcount,
                  uint* __restrict__ gbucket) {
    __shared__ int hist[NBUCK];
    __shared__ int base[NBUCK];
    __shared__ int s_is32;
    const int t = threadIdx.x;
    if (t < NBUCK) hist[t] = 0;
    if (t == 0) s_is32 = 0;
    __syncthreads();
    const int e0 = blockIdx.x * (256 * EPT);
    if (((const int*)ei)[2 * (e0 + t) + 1] != 0) s_is32 = 1;   // dtype probe
    __syncthreads();
    const int is32 = s_is32;
    uint pk[EPT];
    int  rk[EPT];
#pragma unroll
    for (int i = 0; i < EPT; ++i) {
        int e  = e0 + i * 256 + t;
        int s  = edge_at(ei, is32, e);
        int dn = edge_at(ei, is32, N_EDGES + e);
        pk[i] = ((uint)dn << 16) | (uint)s;
        rk[i] = atomicAdd(&hist[dn >> 6], 1);
    }
    __syncthreads();
    if (t < NBUCK) base[t] = atomicAdd(&gcount[t], hist[t]);
    __syncthreads();
#pragma unroll
    for (int i = 0; i < EPT; ++i) {
        int bkt = (int)(pk[i] >> 22);
        int pos = base[bkt] + rk[i];
        if (pos < BCAP) gbucket[(size_t)bkt * BCAP + pos] = pk[i];
    }
}

// ---------------------------------------------------------------------------
// Fused prep (proven R9/R15): [0,157) counting-sort buckets -> padded adj
// (pad = ZROW) + deg; [157,782) cast x -> packed bf16; [782,1038) build WT;
// 1038 zeroes the padding zero-rows of xb2 AND yb2.
__global__ __launch_bounds__(256)
void prep_kernel(const int* __restrict__ gcount, const uint* __restrict__ gbucket,
                 u16* __restrict__ adj, int* __restrict__ deg_g,
                 const float* __restrict__ x, uint* __restrict__ xb2,
                 uint* __restrict__ yb2,
                 const float* __restrict__ Wl0, const float* __restrict__ Wr0,
                 const float* __restrict__ Wl1, const float* __restrict__ Wr1,
                 u16* __restrict__ WT0, u16* __restrict__ WT1) {
    const int b = blockIdx.x;
    const int t = threadIdx.x;
    __shared__ __align__(16) u16 tile[64][MAXDEG];   // 16 KB
    __shared__ int cur[64];
    if (b < NBUCK) {
        uint* tw = (uint*)&tile[0][0];               // pad pattern = ZROW|ZROW
#pragma unroll
        for (int q = 0; q < 16; ++q) tw[t + q * 256] = ((uint)ZROW << 16) | ZROW;
        if (t < 64) cur[t] = 0;
        __syncthreads();
        const int total = min(gcount[b], BCAP);
        for (int e = t; e < total; e += 256) {
            uint pk = gbucket[(size_t)b * BCAP + e];
            int ln = (int)((pk >> 16) & 63u);
            int r = atomicAdd(&cur[ln], 1);
            if (r < MAXDEG) tile[ln][r] = (u16)(pk & 0xffffu);
        }
        __syncthreads();
        const int node0 = b * 64;
        if (t < 64 && node0 + t < N_NODES) deg_g[node0 + t] = cur[t];
        const uint4* ts = (const uint4*)&tile[0][0];
#pragma unroll
        for (int q = 0; q < 4; ++q) {
            int i = t + q * 256;
            int node = node0 + (i >> 4);
            if (node < N_NODES) ((uint4*)(adj + (size_t)node * MAXDEG))[i & 15] = ts[i];
        }
    } else if (b < NBUCK + 625) {
        int idx = (b - NBUCK) * 256 + t;             // 0..159999, exact
        const float4* p = (const float4*)x + (size_t)idx * 2;
        float4 a = p[0], bb = p[1];
        uint4 r;
        r.x = (uint)f2bf(a.x) | ((uint)f2bf(a.y) << 16);
        r.y = (uint)f2bf(a.z) | ((uint)f2bf(a.w) << 16);
        r.z = (uint)f2bf(bb.x) | ((uint)f2bf(bb.y) << 16);
        r.w = (uint)f2bf(bb.z) | ((uint)f2bf(bb.w) << 16);
        ((uint4*)xb2)[idx] = r;
    } else if (b < NBUCK + 625 + 256) {
        int b2 = b - (NBUCK + 625);
        int layer = b2 >> 7, d = b2 & 127, k = t;
        const float* Wl = layer ? Wl1 : Wl0;
        const float* Wr = layer ? Wr1 : Wr0;
        u16* WT = layer ? WT1 : WT0;
        float v = (k < 128) ? Wl[k * D + d] : Wr[(k - 128) * D + d];
        WT[(size_t)d * 256 + k] = f2bf(v);
    } else {
        if (t < 16) {
            ((uint4*)(xb2 + (size_t)ZROW * 64))[t] = make_uint4(0, 0, 0, 0);
            ((uint4*)(yb2 + (size_t)ZROW * 64))[t] = make_uint4(0, 0, 0, 0);
        }
    }
}

// ---------------------------------------------------------------------------
// Fused gather+gemm layer (proven R15): 625 blocks x 1024 threads (16 waves).
// Gather: wave w -> node nb+w (one wave per node, same parallelism as the
// standalone 2500x256 gather). v2 loop: lane (g=l>>4,c=l&15) -> 4 edges x
// uint4 (1 KB/wave-instr); padding ids hit the zero row; shfl_xor reduce;
// g==0 lanes write the bf16 mean row into LDS A (XOR-swizzle (w&7)<<4),
// g==1 lanes write the node's own x row (k 128..255).
// Gemm (waves 0..7): wave w -> cols [w*16, w*16+16); A/B share k-map
// k = kk*32 + q*8 + j (internal permutation cancels); C/D col=lane&15,
// row=(lane>>4)*4+reg [HW-verified].
__global__ __launch_bounds__(1024, 8)
void fused_kernel(const uint* __restrict__ src2, const u16* __restrict__ adj,
                  const int* __restrict__ deg_g, const u16* __restrict__ WT,
                  const float* __restrict__ bias,
                  float* __restrict__ outf /* may be null */,
                  u16* __restrict__ outb /* may be null */) {
    __shared__ __align__(16) u16 A_lds[16 * 256];    // 8 KB
    const int t = threadIdx.x;
    const int w = t >> 6, l = t & 63;
    const int nb = blockIdx.x * 16;
    const int node = nb + w;

    // ---- gather phase (all 16 waves) ----
    {
        const int g = l >> 4, c = l & 15;
        const int half = g >> 1, sh = (g & 1) << 4;
        const int dg = deg_g[node];
        const int cnt = min(dg, MAXDEG);
        const uint4* __restrict__ rowq = (const uint4*)(adj + (size_t)node * MAXDEG);
        float acc[8];
#pragma unroll
        for (int i = 0; i < 8; ++i) acc[i] = 0.f;
        const int nch = (cnt + 15) >> 4;
#pragma unroll 2
        for (int ch = 0; ch < nch; ++ch) {
            uint4 wa = rowq[2 * ch];
            uint4 wb = rowq[2 * ch + 1];
            uint a0 = half ? wa.y : wa.x;
            uint a1 = half ? wa.w : wa.z;
            uint b0 = half ? wb.y : wb.x;
            uint b1 = half ? wb.w : wb.z;
            uint id0 = (a0 >> sh) & 0xffffu;
            uint id1 = (a1 >> sh) & 0xffffu;
            uint id2 = (b0 >> sh) & 0xffffu;
            uint id3 = (b1 >> sh) & 0xffffu;
            uint4 v0 = ((const uint4*)(src2 + (size_t)id0 * 64))[c];
            uint4 v1 = ((const uint4*)(src2 + (size_t)id1 * 64))[c];
            uint4 v2 = ((const uint4*)(src2 + (size_t)id2 * 64))[c];
            uint4 v3 = ((const uint4*)(src2 + (size_t)id3 * 64))[c];
            acc[0] += bflo(v0.x) + bflo(v1.x) + bflo(v2.x) + bflo(v3.x);
            acc[1] += bfhi(v0.x) + bfhi(v1.x) + bfhi(v2.x) + bfhi(v3.x);
            acc[2] += bflo(v0.y) + bflo(v1.y) + bflo(v2.y) + bflo(v3.y);
            acc[3] += bfhi(v0.y) + bfhi(v1.y) + bfhi(v2.y) + bfhi(v3.y);
            acc[4] += bflo(v0.z) + bflo(v1.z) + bflo(v2.z) + bflo(v3.z);
            acc[5] += bfhi(v0.z) + bfhi(v1.z) + bfhi(v2.z) + bfhi(v3.z);
            acc[6] += bflo(v0.w) + bflo(v1.w) + bflo(v2.w) + bflo(v3.w);
            acc[7] += bfhi(v0.w) + bfhi(v1.w) + bfhi(v2.w) + bfhi(v3.w);
        }
#pragma unroll
        for (int i = 0; i < 8; ++i) {
            float r = acc[i];
            r += __shfl_xor(r, 16, 64);
            r += __shfl_xor(r, 32, 64);
            acc[i] = r;
        }
        char* arow = (char*)A_lds + w * 512;
        const int swz = (w & 7) << 4;
        if (g == 0) {                                // agg -> k 0..127
            float inv = 1.0f / fmaxf((float)dg, 1.0f);
            uint4 o;
            o.x = (uint)f2bf(acc[0] * inv) | ((uint)f2bf(acc[1] * inv) << 16);
            o.y = (uint)f2bf(acc[2] * inv) | ((uint)f2bf(acc[3] * inv) << 16);
            o.z = (uint)f2bf(acc[4] * inv) | ((uint)f2bf(acc[5] * inv) << 16);
            o.w = (uint)f2bf(acc[6] * inv) | ((uint)f2bf(acc[7] * inv) << 16);
            *(uint4*)(arow + ((c * 16) ^ swz)) = o;
        } else if (g == 1) {                         // own x/h row -> k 128..255
            uint4 vx = ((const uint4*)(src2 + (size_t)node * 64))[c];
            *(uint4*)(arow + ((256 + c * 16) ^ swz)) = vx;
        }
    }
    __syncthreads();

    // ---- gemm phase (waves 0..7; wave w -> cols [w*16, w*16+16)) ----
    if (w < 8) {
        const int lr = l & 15, q = l >> 4;
        f32x4 acc0 = {0.f, 0.f, 0.f, 0.f};
        const u16* wt = WT + (size_t)(w * 16 + lr) * 256;
        const char* abase = (const char*)A_lds + lr * 512;
        const int aswz = (lr & 7) << 4;
#pragma unroll
        for (int kk = 0; kk < 8; ++kk) {
            bf16x8 af = *(const bf16x8*)(abase + ((kk * 64 + q * 16) ^ aswz));
            bf16x8 bf = *(const bf16x8*)(wt + kk * 32 + q * 8);
            acc0 = __builtin_amdgcn_mfma_f32_16x16x32_bf16(af, bf, acc0, 0, 0, 0);
        }
        const int col = w * 16 + lr;
        const float bv = bias[col];
#pragma unroll
        for (int j = 0; j < 4; ++j) {
            const int nd = nb + q * 4 + j;
            float v = acc0[j] + bv;
            v = v > 0.f ? v : expm1f(v);             // ELU alpha=1
            if (outf) outf[(size_t)nd * D + col] = v;
            if (outb) outb[(size_t)nd * D + col] = f2bf(v);
        }
    }
}

// ---------------------------------------------------------------------------
extern "C" void kernel_launch(void* const* d_in, const int* in_sizes, int n_in,
                              void* d_out, int out_size, void* d_ws, size_t ws_size,
                              hipStream_t stream) {
    const float* x   = (const float*)d_in[0];
    const void*  ei  = d_in[1];
    const float* Wl0 = (const float*)d_in[2];
    const float* b0  = (const float*)d_in[3];
    const float* Wr0 = (const float*)d_in[4];
    const float* Wl1 = (const float*)d_in[5];
    const float* b1  = (const float*)d_in[6];
    const float* Wr1 = (const float*)d_in[7];
    float* out = (float*)d_out;

    char* ws = (char*)d_ws;                      // ws ~268 MB, no overlays
    int*  gcount  = (int*)(ws + 1024);           // 628 B
    int*  deg     = (int*)(ws + 4096);           // 40 KB
    u16*  adj     = (u16*)(ws + 65536);          // 2.56 MB
    uint* gbucket = (uint*)(ws + 3145728);       // 3.86 MB
    uint* xb2     = (uint*)(ws + 7340032);       // 2.56 MB + zrow
    uint* yb2     = (uint*)(ws + 10485760);      // 2.56 MB + zrow
    u16*  WT0     = (u16*)(ws + 13631488);       // 64 KB
    u16*  WT1     = (u16*)(ws + 13697024);       // 64 KB

    (void)hipMemsetAsync(ws, 0, 4096, stream);   // gcount

    binp1_kernel<<<500, 256, 0, stream>>>(ei, gcount, gbucket);
    prep_kernel<<<NBUCK + 625 + 256 + 1, 256, 0, stream>>>(
        gcount, gbucket, adj, deg, x, xb2, yb2, Wl0, Wr0, Wl1, Wr1, WT0, WT1);

    // layer 0: gather xb2 -> gemm -> bf16 activations yb2
    fused_kernel<<<625, 1024, 0, stream>>>(xb2, adj, deg, WT0, b0,
                                           (float*)0, (u16*)yb2);
    // layer 1: gather yb2 -> gemm -> f32 final output
    fused_kernel<<<625, 1024, 0, stream>>>(yb2, adj, deg, WT1, b1,
                                           out, (u16*)0);
}